// Round 1
// baseline (910.329 us; speedup 1.0000x reference)
//
#include <hip/hip_runtime.h>
#include <hip/hip_bf16.h>

// Problem constants (GumbelVectorQuantizer): B=32,T=1536,C=768,G=2,Vg=160
#define BT_TOK   49152      // B*T
#define C_DIM    768
#define NVARS    320        // G*Vg
#define VG       160
#define NGROUPS  2

// ---------------------------------------------------------------------------
// Tiled fp32 GEMM: C[M,N] = A[M,K] @ B[K,N] (+ bias[N] if bias != nullptr)
// BM=BN=64, BK=16, 256 threads, 4x4 micro-tile per thread.
// Requires M%64==0, N%64==0, K%16==0 (true for all shapes here).
// grid = (N/64, M/64)  -- x = n-tile so consecutive blocks share A rows in L2.
// ---------------------------------------------------------------------------
__global__ __launch_bounds__(256)
void sgemm64(const float* __restrict__ A, const float* __restrict__ B,
             const float* __restrict__ bias, float* __restrict__ C,
             int M, int N, int K)
{
    const int tid = threadIdx.x;
    const int n0  = blockIdx.x * 64;
    const int m0  = blockIdx.y * 64;

    __shared__ float As[16][64 + 4];   // [k][m], +4 pad keeps 16B align, kills conflicts
    __shared__ float Bs[16][64];       // [k][n]

    // global-load mapping: 256 threads x float4 = 1024 floats = one 64x16 tile
    const int a_row = tid >> 2;          // 0..63
    const int a_k   = (tid & 3) * 4;     // 0,4,8,12
    const int b_row = tid >> 4;          // 0..15
    const int b_col = (tid & 15) * 4;    // 0..60

    // compute mapping: 16x16 thread grid, 4x4 micro-tile
    const int tx = tid & 15;             // col group -> cols tx*4..tx*4+3
    const int ty = tid >> 4;             // row group -> rows ty*4..ty*4+3

    float acc[4][4] = {};

    for (int k0 = 0; k0 < K; k0 += 16) {
        float4 av = *(const float4*)(A + (size_t)(m0 + a_row) * K + k0 + a_k);
        float4 bv = *(const float4*)(B + (size_t)(k0 + b_row) * N + n0 + b_col);
        __syncthreads();                 // protect previous tile's reads
        As[a_k + 0][a_row] = av.x;
        As[a_k + 1][a_row] = av.y;
        As[a_k + 2][a_row] = av.z;
        As[a_k + 3][a_row] = av.w;
        *(float4*)&Bs[b_row][b_col] = bv;
        __syncthreads();
#pragma unroll
        for (int k = 0; k < 16; ++k) {
            float4 a4 = *(const float4*)&As[k][ty * 4];
            float4 b4 = *(const float4*)&Bs[k][tx * 4];
            const float a[4] = {a4.x, a4.y, a4.z, a4.w};
            const float b[4] = {b4.x, b4.y, b4.z, b4.w};
#pragma unroll
            for (int r = 0; r < 4; ++r)
#pragma unroll
                for (int c = 0; c < 4; ++c)
                    acc[r][c] = fmaf(a[r], b[c], acc[r][c]);
        }
    }

    float4 bs = make_float4(0.f, 0.f, 0.f, 0.f);
    if (bias) bs = *(const float4*)(bias + n0 + tx * 4);
#pragma unroll
    for (int r = 0; r < 4; ++r) {
        float4 o;
        o.x = acc[r][0] + bs.x;
        o.y = acc[r][1] + bs.y;
        o.z = acc[r][2] + bs.z;
        o.w = acc[r][3] + bs.w;
        *(float4*)(C + (size_t)(m0 + ty * 4 + r) * N + n0 + tx * 4) = o;
    }
}

// ---------------------------------------------------------------------------
// Gumbel-softmax over Vg=160 per (token, group), in-place on the logits
// buffer, plus argmax -> codes. One wave (64 lanes) per (token,group):
// lane handles v = lane, lane+64, lane+128 (last only if lane<32).
// y = (logits + gumbel) / TEMP ; probs = softmax(y) ; code = argmax(y).
// ---------------------------------------------------------------------------
__global__ __launch_bounds__(256)
void gumbel_softmax_kernel(float* __restrict__ logits_probs,   // in-place
                           const float* __restrict__ gumbel,
                           float* __restrict__ codes)
{
    const int wid  = (int)((blockIdx.x * (size_t)blockDim.x + threadIdx.x) >> 6);
    const int lane = threadIdx.x & 63;
    if (wid >= BT_TOK * NGROUPS) return;

    float* base       = logits_probs + (size_t)wid * VG;
    const float* gbase = gumbel      + (size_t)wid * VG;

    const float NEG = -3.402823466e+38f;
    float y[3];
    float mx = NEG;
#pragma unroll
    for (int i = 0; i < 3; ++i) {
        int v = lane + i * 64;
        float val = NEG;
        if (v < VG) val = (base[v] + gbase[v]) * 0.5f;   // /TEMP, TEMP=2.0
        y[i] = val;
        mx = fmaxf(mx, val);
    }
#pragma unroll
    for (int off = 32; off > 0; off >>= 1)
        mx = fmaxf(mx, __shfl_xor(mx, off, 64));

    float e[3];
    float s = 0.f;
#pragma unroll
    for (int i = 0; i < 3; ++i) {
        int v = lane + i * 64;
        e[i] = (v < VG) ? expf(y[i] - mx) : 0.f;
        s += e[i];
    }
#pragma unroll
    for (int off = 32; off > 0; off >>= 1)
        s += __shfl_xor(s, off, 64);
    const float inv = 1.0f / s;

#pragma unroll
    for (int i = 0; i < 3; ++i) {
        int v = lane + i * 64;
        if (v < VG) base[v] = e[i] * inv;
    }

    // argmax (first-occurrence tie-break; strict > keeps lowest index per lane)
    float bv = y[0];
    int   bi = lane;
#pragma unroll
    for (int i = 1; i < 3; ++i) {
        int v = lane + i * 64;
        if (v < VG && y[i] > bv) { bv = y[i]; bi = v; }
    }
#pragma unroll
    for (int off = 32; off > 0; off >>= 1) {
        float ov = __shfl_xor(bv, off, 64);
        int   oi = __shfl_xor(bi, off, 64);
        if (ov > bv || (ov == bv && oi < bi)) { bv = ov; bi = oi; }
    }
    if (lane == 0) codes[wid] = (float)bi;
}

// ---------------------------------------------------------------------------
extern "C" void kernel_launch(void* const* d_in, const int* in_sizes, int n_in,
                              void* d_out, int out_size, void* d_ws, size_t ws_size,
                              hipStream_t stream) {
    const float* x        = (const float*)d_in[0];   // (BT, 768)
    const float* gumbel   = (const float*)d_in[1];   // (BT, 320) == (B,T,G,Vg)
    const float* W_proj   = (const float*)d_in[2];   // (768, 320)
    const float* b_proj   = (const float*)d_in[3];   // (320,)
    const float* codebook = (const float*)d_in[4];   // (320, 768) == (G,Vg,C)

    float* quantized = (float*)d_out;                                // 37,748,736
    float* codes     = quantized + (size_t)BT_TOK * C_DIM;           //     98,304
    float* probs     = codes + (size_t)BT_TOK * NGROUPS;             // 15,728,640

    // 1) logits = x @ W_proj + b  -> write into probs region (reused in-place)
    {
        dim3 grid(NVARS / 64, BT_TOK / 64);   // (5, 768)
        sgemm64<<<grid, 256, 0, stream>>>(x, W_proj, b_proj, probs,
                                          BT_TOK, NVARS, C_DIM);
    }
    // 2) gumbel-softmax in-place + codes
    {
        int nwaves = BT_TOK * NGROUPS;        // 98304
        int blocks = nwaves / 4;              // 4 waves per 256-thread block
        gumbel_softmax_kernel<<<blocks, 256, 0, stream>>>(probs, gumbel, codes);
    }
    // 3) quantized = probs @ codebook
    {
        dim3 grid(C_DIM / 64, BT_TOK / 64);   // (12, 768)
        sgemm64<<<grid, 256, 0, stream>>>(probs, codebook, nullptr, quantized,
                                          BT_TOK, C_DIM, NVARS);
    }
}

// Round 2
// 687.960 us; speedup vs baseline: 1.3232x; 1.3232x over previous
//
#include <hip/hip_runtime.h>
#include <hip/hip_bf16.h>
#include <stdint.h>

// Problem constants (GumbelVectorQuantizer): B=32,T=1536,C=768,G=2,Vg=160
#define BT_TOK   49152      // B*T
#define C_DIM    768
#define NVARS    320        // G*Vg
#define VG       160
#define NGROUPS  2

// ---------------------------------------------------------------------------
// bf16 helpers (RNE, branch-free; inputs are finite)
// ---------------------------------------------------------------------------
__device__ __forceinline__ unsigned short bf16_rne(float f) {
    union { float f; uint32_t u; } v; v.f = f;
    uint32_t u = v.u + 0x7FFFu + ((v.u >> 16) & 1u);
    return (unsigned short)(u >> 16);
}
__device__ __forceinline__ float bf16_to_f(unsigned short h) {
    union { uint32_t u; float f; } v; v.u = ((uint32_t)h) << 16;
    return v.f;
}

typedef __attribute__((ext_vector_type(8))) short bf16x8;   // 8 bf16 = 4 VGPRs
typedef __attribute__((ext_vector_type(4))) float f32x4;

#define GLOBAL_AS __attribute__((address_space(1)))
#define LDS_AS    __attribute__((address_space(3)))
__device__ __forceinline__ void gl2lds16(const void* g, void* l) {
    // width=16 global->LDS DMA; LDS dest is wave-uniform base + lane*16
    __builtin_amdgcn_global_load_lds((const GLOBAL_AS void*)g, (LDS_AS void*)l, 16, 0, 0);
}

// ---------------------------------------------------------------------------
// Prepass: fp32 -> (hi, lo) bf16 split, elementwise. n must be %1024 == 0.
// ---------------------------------------------------------------------------
__global__ __launch_bounds__(256)
void split_convert(const float* __restrict__ in, unsigned short* __restrict__ hi,
                   unsigned short* __restrict__ lo, int n) {
    int i = (blockIdx.x * 256 + threadIdx.x) * 4;
    if (i >= n) return;
    float4 v = *(const float4*)(in + i);
    ushort4 h, l;
    h.x = bf16_rne(v.x); l.x = bf16_rne(v.x - bf16_to_f(h.x));
    h.y = bf16_rne(v.y); l.y = bf16_rne(v.y - bf16_to_f(h.y));
    h.z = bf16_rne(v.z); l.z = bf16_rne(v.z - bf16_to_f(h.z));
    h.w = bf16_rne(v.w); l.w = bf16_rne(v.w - bf16_to_f(h.w));
    *(ushort4*)(hi + i) = h;
    *(ushort4*)(lo + i) = l;
}

// ---------------------------------------------------------------------------
// Prepass: transpose (K x N fp32) -> (N x K) bf16 hi/lo. Tiny matrices.
// grid = (ceil(K/256), N)
// ---------------------------------------------------------------------------
__global__ __launch_bounds__(256)
void transpose_split(const float* __restrict__ in, unsigned short* __restrict__ hi,
                     unsigned short* __restrict__ lo, int K, int N) {
    int k = blockIdx.x * 256 + threadIdx.x;
    int n = blockIdx.y;
    if (k >= K) return;
    float f = in[(size_t)k * N + n];
    unsigned short h = bf16_rne(f);
    hi[(size_t)n * K + k] = h;
    lo[(size_t)n * K + k] = bf16_rne(f - bf16_to_f(h));
}

// ---------------------------------------------------------------------------
// Split-bf16 GEMM: C[M,N] = (Ahi+Alo)[M,K] @ (Bhi+Blo)[K,N] (+bias), where
// B is given TRANSPOSED (N x K, k-contiguous). 3 MFMAs per logical tile
// (hi*hi + hi*lo + lo*hi), fp32 accumulate -> error ~ fp32 level.
// Block tile BM x BN, BK=32, WM x WN waves, each wave computes 64x64.
// LDS layout per tile row: 32 bf16 = 4 chunks of 16B, chunk position XOR-
// swizzled by ((row>>1)&3) so frag ds_read_b128 is ~2-way (free).
// ---------------------------------------------------------------------------
template<int BM, int BN, int WM, int WN>
__global__ __launch_bounds__(WM*WN*64)
void gemm_split(const unsigned short* __restrict__ Ahi, const unsigned short* __restrict__ Alo,
                const unsigned short* __restrict__ Bthi, const unsigned short* __restrict__ Btlo,
                const float* __restrict__ bias, float* __restrict__ C,
                int M, int N, int K)
{
    constexpr int NW = WM * WN;
    constexpr int nIterA = (BM * 4) / 64;   // wave-issues per A buffer per K-step
    constexpr int nIterB = (BN * 4) / 64;

    __shared__ __align__(16) unsigned short sAh[BM * 32];
    __shared__ __align__(16) unsigned short sAl[BM * 32];
    __shared__ __align__(16) unsigned short sBh[BN * 32];
    __shared__ __align__(16) unsigned short sBl[BN * 32];

    const int tid  = threadIdx.x;
    const int lane = tid & 63;
    const int wid  = tid >> 6;
    const int wm   = wid % WM;
    const int wn   = wid / WM;
    const int m0   = blockIdx.y * BM;
    const int n0   = blockIdx.x * BN;

    const int r15 = lane & 15;   // row-within-16 for frags
    const int q   = lane >> 4;   // k-chunk for frags

    f32x4 acc[4][4];
#pragma unroll
    for (int i = 0; i < 4; ++i)
#pragma unroll
        for (int j = 0; j < 4; ++j) {
            f32x4 z = {0.f, 0.f, 0.f, 0.f};
            acc[i][j] = z;
        }

    for (int k0 = 0; k0 < K; k0 += 32) {
        // ---- stage A/B hi+lo tiles into LDS via global_load_lds (16B/lane)
        for (int i = wid; i < nIterA; i += NW) {
            int slot = i * 64 + lane;
            int row  = slot >> 2, cs = slot & 3;
            int c    = cs ^ ((row >> 1) & 3);          // logical chunk at this slot
            size_t goff = (size_t)(m0 + row) * K + k0 + c * 8;
            gl2lds16(Ahi + goff, (char*)sAh + i * 1024);
            gl2lds16(Alo + goff, (char*)sAl + i * 1024);
        }
        for (int i = wid; i < nIterB; i += NW) {
            int slot = i * 64 + lane;
            int row  = slot >> 2, cs = slot & 3;
            int c    = cs ^ ((row >> 1) & 3);
            size_t goff = (size_t)(n0 + row) * K + k0 + c * 8;
            gl2lds16(Bthi + goff, (char*)sBh + i * 1024);
            gl2lds16(Btlo + goff, (char*)sBl + i * 1024);
        }
        __syncthreads();   // drains vmcnt -> staged data visible

        // ---- LDS -> frags (swizzled ds_read_b128)
        bf16x8 ah[4], al[4], bh[4], bl[4];
#pragma unroll
        for (int mi = 0; mi < 4; ++mi) {
            int row = wm * 64 + mi * 16 + r15;
            int off = row * 32 + ((q ^ ((row >> 1) & 3)) * 8);
            ah[mi] = *(const bf16x8*)&sAh[off];
            al[mi] = *(const bf16x8*)&sAl[off];
        }
#pragma unroll
        for (int ni = 0; ni < 4; ++ni) {
            int row = wn * 64 + ni * 16 + r15;
            int off = row * 32 + ((q ^ ((row >> 1) & 3)) * 8);
            bh[ni] = *(const bf16x8*)&sBh[off];
            bl[ni] = *(const bf16x8*)&sBl[off];
        }

        // ---- MFMA: hi*hi + hi*lo + lo*hi
#pragma unroll
        for (int mi = 0; mi < 4; ++mi)
#pragma unroll
            for (int ni = 0; ni < 4; ++ni) {
                acc[mi][ni] = __builtin_amdgcn_mfma_f32_16x16x32_bf16(ah[mi], bh[ni], acc[mi][ni], 0, 0, 0);
                acc[mi][ni] = __builtin_amdgcn_mfma_f32_16x16x32_bf16(ah[mi], bl[ni], acc[mi][ni], 0, 0, 0);
                acc[mi][ni] = __builtin_amdgcn_mfma_f32_16x16x32_bf16(al[mi], bh[ni], acc[mi][ni], 0, 0, 0);
            }
        __syncthreads();   // all reads done before next-stage overwrite
    }

    // ---- epilogue: C/D layout col=lane&15, row=quad*4+reg (m89/m91-verified)
#pragma unroll
    for (int ni = 0; ni < 4; ++ni) {
        int col = n0 + wn * 64 + ni * 16 + r15;
        float bv = bias ? bias[col] : 0.f;
#pragma unroll
        for (int mi = 0; mi < 4; ++mi) {
            int rbase = m0 + wm * 64 + mi * 16 + q * 4;
#pragma unroll
            for (int rr = 0; rr < 4; ++rr)
                C[(size_t)(rbase + rr) * N + col] = acc[mi][ni][rr] + bv;
        }
    }
}

// ---------------------------------------------------------------------------
// Gumbel-softmax over Vg=160 per (token, group), in-place on logits buffer.
// Also emits probs as bf16 hi/lo split (for the split-bf16 GEMM2) when
// phi/plo are non-null. One wave per (token,group).
// ---------------------------------------------------------------------------
__global__ __launch_bounds__(256)
void gumbel_softmax_kernel(float* __restrict__ logits_probs,
                           const float* __restrict__ gumbel,
                           float* __restrict__ codes,
                           unsigned short* __restrict__ phi,
                           unsigned short* __restrict__ plo)
{
    const int wid  = (int)((blockIdx.x * (size_t)blockDim.x + threadIdx.x) >> 6);
    const int lane = threadIdx.x & 63;
    if (wid >= BT_TOK * NGROUPS) return;

    float* base        = logits_probs + (size_t)wid * VG;
    const float* gbase = gumbel       + (size_t)wid * VG;

    const float NEG = -3.402823466e+38f;
    float y[3];
    float mx = NEG;
#pragma unroll
    for (int i = 0; i < 3; ++i) {
        int v = lane + i * 64;
        float val = NEG;
        if (v < VG) val = (base[v] + gbase[v]) * 0.5f;   // /TEMP, TEMP=2.0
        y[i] = val;
        mx = fmaxf(mx, val);
    }
#pragma unroll
    for (int off = 32; off > 0; off >>= 1)
        mx = fmaxf(mx, __shfl_xor(mx, off, 64));

    float e[3];
    float s = 0.f;
#pragma unroll
    for (int i = 0; i < 3; ++i) {
        int v = lane + i * 64;
        e[i] = (v < VG) ? expf(y[i] - mx) : 0.f;
        s += e[i];
    }
#pragma unroll
    for (int off = 32; off > 0; off >>= 1)
        s += __shfl_xor(s, off, 64);
    const float inv = 1.0f / s;

#pragma unroll
    for (int i = 0; i < 3; ++i) {
        int v = lane + i * 64;
        if (v < VG) {
            float p = e[i] * inv;
            base[v] = p;
            if (phi) {
                unsigned short h = bf16_rne(p);
                phi[(size_t)wid * VG + v] = h;
                plo[(size_t)wid * VG + v] = bf16_rne(p - bf16_to_f(h));
            }
        }
    }

    // argmax (first-occurrence tie-break)
    float bv = y[0];
    int   bi = lane;
#pragma unroll
    for (int i = 1; i < 3; ++i) {
        int v = lane + i * 64;
        if (v < VG && y[i] > bv) { bv = y[i]; bi = v; }
    }
#pragma unroll
    for (int off = 32; off > 0; off >>= 1) {
        float ov = __shfl_xor(bv, off, 64);
        int   oi = __shfl_xor(bi, off, 64);
        if (ov > bv || (ov == bv && oi < bi)) { bv = ov; bi = oi; }
    }
    if (lane == 0) codes[wid] = (float)bi;
}

// ---------------------------------------------------------------------------
// Fallback fp32 tiled GEMM (round-1 kernel, known-good) if ws is too small.
// ---------------------------------------------------------------------------
__global__ __launch_bounds__(256)
void sgemm64(const float* __restrict__ A, const float* __restrict__ B,
             const float* __restrict__ bias, float* __restrict__ C,
             int M, int N, int K)
{
    const int tid = threadIdx.x;
    const int n0  = blockIdx.x * 64;
    const int m0  = blockIdx.y * 64;

    __shared__ float As[16][64 + 4];
    __shared__ float Bs[16][64];

    const int a_row = tid >> 2;
    const int a_k   = (tid & 3) * 4;
    const int b_row = tid >> 4;
    const int b_col = (tid & 15) * 4;
    const int tx = tid & 15;
    const int ty = tid >> 4;

    float acc[4][4] = {};

    for (int k0 = 0; k0 < K; k0 += 16) {
        float4 av = *(const float4*)(A + (size_t)(m0 + a_row) * K + k0 + a_k);
        float4 bv = *(const float4*)(B + (size_t)(k0 + b_row) * N + n0 + b_col);
        __syncthreads();
        As[a_k + 0][a_row] = av.x;
        As[a_k + 1][a_row] = av.y;
        As[a_k + 2][a_row] = av.z;
        As[a_k + 3][a_row] = av.w;
        *(float4*)&Bs[b_row][b_col] = bv;
        __syncthreads();
#pragma unroll
        for (int k = 0; k < 16; ++k) {
            float4 a4 = *(const float4*)&As[k][ty * 4];
            float4 b4 = *(const float4*)&Bs[k][tx * 4];
            const float a[4] = {a4.x, a4.y, a4.z, a4.w};
            const float b[4] = {b4.x, b4.y, b4.z, b4.w};
#pragma unroll
            for (int r = 0; r < 4; ++r)
#pragma unroll
                for (int c = 0; c < 4; ++c)
                    acc[r][c] = fmaf(a[r], b[c], acc[r][c]);
        }
    }

    float4 bs = make_float4(0.f, 0.f, 0.f, 0.f);
    if (bias) bs = *(const float4*)(bias + n0 + tx * 4);
#pragma unroll
    for (int r = 0; r < 4; ++r) {
        float4 o;
        o.x = acc[r][0] + bs.x;
        o.y = acc[r][1] + bs.y;
        o.z = acc[r][2] + bs.z;
        o.w = acc[r][3] + bs.w;
        *(float4*)(C + (size_t)(m0 + ty * 4 + r) * N + n0 + tx * 4) = o;
    }
}

// ---------------------------------------------------------------------------
extern "C" void kernel_launch(void* const* d_in, const int* in_sizes, int n_in,
                              void* d_out, int out_size, void* d_ws, size_t ws_size,
                              hipStream_t stream) {
    const float* x        = (const float*)d_in[0];   // (BT, 768)
    const float* gumbel   = (const float*)d_in[1];   // (BT, 320)
    const float* W_proj   = (const float*)d_in[2];   // (768, 320)
    const float* b_proj   = (const float*)d_in[3];   // (320,)
    const float* codebook = (const float*)d_in[4];   // (320, 768)

    float* quantized = (float*)d_out;
    float* codes     = quantized + (size_t)BT_TOK * C_DIM;
    float* probs     = codes + (size_t)BT_TOK * NGROUPS;   // logits, then probs in-place

    // workspace layout (bytes)
    const size_t SZ_X  = (size_t)BT_TOK * C_DIM * 2;   // 75,497,472 per buffer
    const size_t SZ_P  = (size_t)BT_TOK * NVARS * 2;   // 31,457,280
    const size_t SZ_W  = (size_t)C_DIM * NVARS * 2;    //    491,520
    const size_t need  = 2 * SZ_X + 2 * SZ_P + 4 * SZ_W;   // 215,875,584

    if (ws_size >= need) {
        char* ws = (char*)d_ws;
        unsigned short* xhi  = (unsigned short*)(ws);
        unsigned short* xlo  = (unsigned short*)(ws + SZ_X);
        unsigned short* wthi = (unsigned short*)(ws + 2 * SZ_X);
        unsigned short* wtlo = (unsigned short*)(ws + 2 * SZ_X + SZ_W);
        unsigned short* cthi = (unsigned short*)(ws + 2 * SZ_X + 2 * SZ_W);
        unsigned short* ctlo = (unsigned short*)(ws + 2 * SZ_X + 3 * SZ_W);
        unsigned short* phi  = (unsigned short*)(ws + 2 * SZ_X + 4 * SZ_W);
        unsigned short* plo  = (unsigned short*)(ws + 2 * SZ_X + 4 * SZ_W + SZ_P);

        // prepasses
        split_convert<<<(BT_TOK * C_DIM / 4 + 255) / 256, 256, 0, stream>>>(
            x, xhi, xlo, BT_TOK * C_DIM);
        transpose_split<<<dim3((C_DIM + 255) / 256, NVARS), 256, 0, stream>>>(
            W_proj, wthi, wtlo, C_DIM, NVARS);
        transpose_split<<<dim3((NVARS + 255) / 256, C_DIM), 256, 0, stream>>>(
            codebook, cthi, ctlo, NVARS, C_DIM);

        // GEMM1: logits = x @ W + b   (M=BT, N=320, K=768), 128x64 tile, 2 waves
        gemm_split<128, 64, 2, 1><<<dim3(NVARS / 64, BT_TOK / 128), 128, 0, stream>>>(
            xhi, xlo, wthi, wtlo, b_proj, probs, BT_TOK, NVARS, C_DIM);

        // softmax + codes + probs hi/lo
        gumbel_softmax_kernel<<<BT_TOK * NGROUPS / 4, 256, 0, stream>>>(
            probs, gumbel, codes, phi, plo);

        // GEMM2: quantized = probs @ codebook  (M=BT, N=768, K=320), 128x128, 4 waves
        gemm_split<128, 128, 2, 2><<<dim3(C_DIM / 128, BT_TOK / 128), 256, 0, stream>>>(
            phi, plo, cthi, ctlo, nullptr, quantized, BT_TOK, C_DIM, NVARS);
    } else {
        // fallback: known-good fp32 path
        dim3 g1(NVARS / 64, BT_TOK / 64);
        sgemm64<<<g1, 256, 0, stream>>>(x, W_proj, b_proj, probs, BT_TOK, NVARS, C_DIM);
        gumbel_softmax_kernel<<<BT_TOK * NGROUPS / 4, 256, 0, stream>>>(
            probs, gumbel, codes, nullptr, nullptr);
        dim3 g2(C_DIM / 64, BT_TOK / 64);
        sgemm64<<<g2, 256, 0, stream>>>(probs, codebook, nullptr, quantized, BT_TOK, C_DIM, NVARS);
    }
}